// Round 6
// baseline (111.883 us; speedup 1.0000x reference)
//
#include <hip/hip_runtime.h>

// C51 distributional projection — zero-atomic scan + software-pipelined slabs.
//
// R5 post-mortem: pipelined version FAILED because the scan's row read was
// moved inside the scan loop; with the in-place LDS update, writes of
// finalized bins can overtake reads (whenever lower_j > j, e.g. positive
// rewards or bootstrap==0 rows) and destroy unread input. R3/R4 passed
// because the row was buffered in registers BEFORE scanning. This version
// restores the register row-buffer (d[51]) and keeps the R5 pipeline.
//
// Pipeline per 1-wave workgroup (4 slabs x 64 rows, 13 KB LDS, ~12 wg/CU):
//   stage slab k (ds_write regs loaded last iter) -> issue slab k+1's 13
//   global_load_dwordx4 into regs -> scan slab k (row -> d[51] regs, then
//   monotone sliding 2-register scan, in-place ds_write) -> coalesced store.
//   Loads stay in flight across the ~2800-cycle scan -> high issue duty.
//
// VGPR note: d[51] + stage[52] + misc ~ 130 live regs. LDS caps occupancy at
// 12 wg/CU = 3 waves/SIMD, and 512/3 = 170 VGPRs/wave at that occupancy, so
// this register usage is occupancy-free. __launch_bounds__(64,3) tells the
// allocator.

namespace {

constexpr int NA    = 51;
constexpr int BLOCK = 64;            // one wave; lanes == rows per slab
constexpr int ROWS  = 64;
constexpr int NSLAB = 4;             // slabs per workgroup
constexpr int ELEMS = ROWS * NA;     // 3264 floats = 13,056 B LDS
constexpr int VECS  = ELEMS / 4;     // 816 float4s
constexpr int VPL   = 13;            // vec iters per lane (last: tid<48)

// Row projection: buffer the row in registers FIRST (in-place LDS write below
// may overtake lds reads otherwise — the R5 bug), then sliding scan.
// b_j = clip(2.5r + 25 + 0.99*beta*(j-25)*..., 0, 50) is monotone in j with
// step 0.99 < 1; after integer-bin adjust upper == lower+1, so targets
// advance 0/1 per atom and each bin is emitted exactly once.
__device__ __forceinline__ void scan_row(float r, float g, int rb, float* lds)
{
    float d[NA];
    #pragma unroll
    for (int j = 0; j < NA; ++j) d[j] = lds[rb + j];   // static unroll -> regs

    int   cur  = 0;
    float accL = 0.0f, accU = 0.0f;

    #pragma unroll
    for (int j = 0; j < NA; ++j) {
        const float z = fmaf((float)j, 0.4f, -10.0f);  // support atom z_j
        float t = fmaf(g, z, r);                       // r + 0.99*beta*z_j
        t = fminf(fmaxf(t, -10.0f), 10.0f);
        const float b = (t + 10.0f) * 2.5f;            // in [0, 50]

        const float lf = floorf(b);
        int lower = (int)lf;
        if (b == lf && lower > 0) lower -= 1;          // integer-bin adjust
        // invariant: upper == lower + 1, lower in [0,49]

        const float wl = d[j] * ((float)(lower + 1) - b);
        const float wu = d[j] * (b - (float)lower);

        while (cur < lower) {                          // emit finalized bins
            lds[rb + cur] = accL;
            accL = accU; accU = 0.0f; ++cur;
        }
        accL += wl;
        accU += wu;
    }
    lds[rb + cur]     = accL;
    lds[rb + cur + 1] = accU;                          // cur+1 <= 50
    for (int k = cur + 2; k < NA; ++k) lds[rb + k] = 0.0f;
}

__global__ __launch_bounds__(BLOCK, 3)
void c51_project(const float* __restrict__ next_dist,
                 const float* __restrict__ rewards,
                 const float* __restrict__ bootstrap,
                 float* __restrict__ out,
                 int B)
{
    __shared__ __align__(16) float lds[ELEMS];

    const int tid = threadIdx.x;
    const long long wg_row0 = (long long)blockIdx.x * (ROWS * NSLAB);
    const bool wg_full = (wg_row0 + ROWS * NSLAB) <= (long long)B;

    if (wg_full) {
        // ---- fast path: software-pipelined over 4 full slabs ----
        float r[NSLAB], g[NSLAB];
        #pragma unroll
        for (int k = 0; k < NSLAB; ++k) {
            const long long row = wg_row0 + (long long)k * ROWS + tid;
            r[k] = rewards[row];
            g[k] = bootstrap[row] * 0.99f;
        }

        // prologue: issue slab 0's loads
        float4 stage[VPL];
        {
            const float4* __restrict__ in4 =
                (const float4*)(next_dist + wg_row0 * NA);
            #pragma unroll
            for (int i = 0; i < VPL; ++i) {
                const int v = tid + i * BLOCK;
                if (v < VECS) stage[i] = in4[v];
            }
        }

        #pragma unroll
        for (int k = 0; k < NSLAB; ++k) {
            // stage slab k into LDS (compiler's vmcnt waits land here)
            {
                float4* l4 = (float4*)lds;
                #pragma unroll
                for (int i = 0; i < VPL; ++i) {
                    const int v = tid + i * BLOCK;
                    if (v < VECS) l4[v] = stage[i];
                }
            }
            // issue slab k+1's loads NOW — they fly during the scan
            if (k + 1 < NSLAB) {
                const float4* __restrict__ in4 =
                    (const float4*)(next_dist + (wg_row0 + (long long)(k + 1) * ROWS) * NA);
                #pragma unroll
                for (int i = 0; i < VPL; ++i) {
                    const int v = tid + i * BLOCK;
                    if (v < VECS) stage[i] = in4[v];
                }
            }
            __syncthreads();          // 1-wave wg: cheap; pins IR ordering

            scan_row(r[k], g[k], tid * NA, lds);   // in-place projection

            __syncthreads();

            // coalesced store of slab k
            {
                float4* __restrict__ o4 =
                    (float4*)(out + (wg_row0 + (long long)k * ROWS) * NA);
                const float4* __restrict__ a4 = (const float4*)lds;
                #pragma unroll
                for (int i = 0; i < VPL; ++i) {
                    const int v = tid + i * BLOCK;
                    if (v < VECS) o4[v] = a4[v];
                }
            }
            // next iter's ds_writes follow this iter's ds_reads in program
            // order (same-wave DS ops retire in order) — no extra barrier.
        }
    } else {
        // ---- tail path (last workgroup only): guarded, unpipelined ----
        for (int k = 0; k < NSLAB; ++k) {
            const long long base_row = wg_row0 + (long long)k * ROWS;
            const int rows_here = (int)min((long long)ROWS, (long long)B - base_row);
            if (rows_here <= 0) break;
            const int elems_here = rows_here * NA;
            const long long base_elem = base_row * NA;

            float r = 0.0f, g = 0.0f;
            if (tid < rows_here) {
                r = rewards[base_row + tid];
                g = bootstrap[base_row + tid] * 0.99f;
            }
            for (int e = tid; e < elems_here; e += BLOCK)
                lds[e] = next_dist[base_elem + e];
            __syncthreads();
            if (tid < rows_here) scan_row(r, g, tid * NA, lds);
            __syncthreads();
            for (int e = tid; e < elems_here; e += BLOCK)
                out[base_elem + e] = lds[e];
            __syncthreads();
        }
    }
}

} // namespace

extern "C" void kernel_launch(void* const* d_in, const int* in_sizes, int n_in,
                              void* d_out, int out_size, void* d_ws, size_t ws_size,
                              hipStream_t stream)
{
    const float* next_dist = (const float*)d_in[0];
    const float* rewards   = (const float*)d_in[1];
    const float* bootstrap = (const float*)d_in[2];
    float* out = (float*)d_out;

    const int B = in_sizes[1];                          // rewards element count
    const int rows_per_wg = ROWS * NSLAB;               // 256
    const int nblocks = (B + rows_per_wg - 1) / rows_per_wg;  // 2048 for B=524288

    c51_project<<<dim3(nblocks), dim3(BLOCK), 0, stream>>>(
        next_dist, rewards, bootstrap, out, B);
}